// Round 22
// baseline (240.732 us; speedup 1.0000x reference)
//
#include <hip/hip_runtime.h>
#include <math.h>

#define Bn 8
#define Cn 64
#define Hn 96
#define Wn 96
#define HWn (Hn*Wn)
#define OCn 64
#define Kn 9
#define OFFCn 27
#define NPIX (Bn*HWn)        // 73728 = 1152*64
#define PGRPS (NPIX/64)      // 1152 pixel groups
#define BLK_PER_B (HWn/64)   // 144 blocks per batch image

// ws layout (dwords): pwbuf[36*NPIX] | abuf[9*NPIX] | wpk1[15552] | wpk2m shorts | x2
#define WPK1_N 15552
#define WPK2M_SHORTS 131072
#define X2_ELEMS (Bn*Cn*HWn)                 // 4718592 float2 = 37.7 MB
#define WS_DWORDS  (45*NPIX + WPK1_N + WPK2M_SHORTS/2)
#define WS_BYTES   ((size_t)WS_DWORDS*4)                 // ~13.9 MB
#define WS2_BYTES  (WS_BYTES + (size_t)X2_ELEMS*8)       // ~51.7 MB

typedef __attribute__((ext_vector_type(8))) short short8v;
typedef __attribute__((ext_vector_type(4))) float f32x4;

static __device__ __forceinline__ unsigned short bf16_rne(float f) {
    unsigned int u = __float_as_uint(f);
    return (unsigned short)((u + 0x7FFFu + ((u >> 16) & 1u)) >> 16);
}
static __device__ __forceinline__ float bf16_back(unsigned short h) {
    return __uint_as_float(((unsigned int)h) << 16);
}

// ============ wprep: wpk1 stream (offset conv) + wpk2m MFMA A-frags ===========
__global__ __launch_bounds__(256) void dcn_wprep(
    const float* __restrict__ w_off,
    const float* __restrict__ weight,
    float* __restrict__ wpk1,
    short* __restrict__ wpk2m)
{
    const int g = blockIdx.x * 256 + threadIdx.x;   // 64 blocks -> 16384
    if (g < WPK1_N) {
        const int c_all = g / 243;
        const int och   = (g % 243) / 9;
        const int ki    = g % 9;
        wpk1[g] = w_off[(och * 64 + c_all) * 9 + ki];
    }
    if (g < WPK2M_SHORTS / 8) {
        const int lane = g & 63;
        const int oct  = (g >> 6) & 3;
        const int c    = g >> 8;
        const int oc   = oct * 16 + (lane & 15);
        const float* wsrc = weight + (oc * 64 + c) * 9;
        short8v v;
#pragma unroll
        for (int j = 0; j < 8; ++j) {
            const int s = ((lane >> 4) & 3) * 8 + j;
            float f = 0.0f;
            if (s <= 8)                  f = wsrc[s];
            else if (s >= 16 && s <= 24) f = wsrc[s - 16];
            v[j] = (short)bf16_rne(f);
        }
        ((short8v*)wpk2m)[g] = v;
    }
}

// ============ xprep: pair-interleave x -> x2[i] = {x[i], x[i+1]} =============
__global__ __launch_bounds__(256) void dcn_xprep(
    const float* __restrict__ x, float2* __restrict__ x2)
{
    const int g = blockIdx.x * 256 + threadIdx.x;
    if (g < X2_ELEMS) {
        const float a = x[g];
        const float c = (g + 1 < X2_ELEMS) ? x[g + 1] : 0.0f;
        x2[g] = make_float2(a, c);
    }
}

// ============================ K1: offset conv + sampling params (swizzled) ====
__global__ __launch_bounds__(256, 2) void dcn_k1(
    const float* __restrict__ x,
    const float* __restrict__ wpk1,
    const float* __restrict__ b_off,
    float* __restrict__ pwbuf,
    int*   __restrict__ abuf)
{
    __shared__ float lds[4 * 64 * OFFCn];   // 27.6 KB

    const int tid  = threadIdx.x;
    const int lane = tid & 63;
    const int wv   = tid >> 6;
    const int cbase = __builtin_amdgcn_readfirstlane(wv * 16);

    const int bid = (blockIdx.x & 7) * BLK_PER_B + (blockIdx.x >> 3);

    const int p  = bid * 64 + lane;
    const int b  = p / HWn;
    const int hw = p % HWn;
    const int ho = hw / Wn;
    const int wo = hw % Wn;

    const float* xb = x + b * (Cn * HWn);

    int   toff[Kn];
    float tval[Kn];
#pragma unroll
    for (int ki = 0; ki < Kn; ++ki) {
        const int yy = ho + ki / 3 - 1, xx = wo + ki % 3 - 1;
        const bool v = (yy >= 0) && (yy < Hn) && (xx >= 0) && (xx < Wn);
        toff[ki] = min(max(yy, 0), Hn - 1) * Wn + min(max(xx, 0), Wn - 1);
        tval[ki] = v ? 1.0f : 0.0f;
    }

    float om[OFFCn];
#pragma unroll
    for (int j = 0; j < OFFCn; ++j) om[j] = 0.0f;

    const float* wstream = wpk1 + cbase * 243;
    for (int ci = 0; ci < 16; ++ci) {
        const float* xc = xb + (cbase + ci) * HWn;
        float xk[Kn];
#pragma unroll
        for (int ki = 0; ki < Kn; ++ki)
            xk[ki] = xc[toff[ki]] * tval[ki];

        const float* wc = wstream + ci * 243;
#pragma unroll
        for (int och = 0; och < OFFCn; ++och) {
            const float* wp = wc + och * 9;
            float a = om[och];
#pragma unroll
            for (int ki = 0; ki < Kn; ++ki)
                a = fmaf(xk[ki], wp[ki], a);
            om[och] = a;
        }
    }

#pragma unroll
    for (int j = 0; j < OFFCn; ++j)
        lds[(wv * 64 + lane) * OFFCn + j] = om[j];
    __syncthreads();
#pragma unroll
    for (int j = 0; j < OFFCn; ++j) {
        float a = b_off[j];
#pragma unroll
        for (int ww = 0; ww < 4; ++ww)
            a += lds[(ww * 64 + lane) * OFFCn + j];
        om[j] = a;
    }

    float pw0[Kn], pw1[Kn], pw2[Kn], pw3[Kn];
    int   pav[Kn];
#pragma unroll
    for (int ki = 0; ki < Kn; ++ki) {
        const float py = om[ki]      + (float)(ki / 3 + ho - 1);
        const float px = om[Kn + ki] + (float)(ki % 3 + wo - 1);
        const float m  = 1.0f / (1.0f + __expf(-om[2 * Kn + ki]));

        const float y0f = floorf(py), x0f = floorf(px);
        const float ly = py - y0f, lx = px - x0f;
        const int iy0 = (int)y0f, ix0 = (int)x0f;
        const int iy1 = iy0 + 1,  ix1 = ix0 + 1;

        const float vy0 = (iy0 >= 0 && iy0 < Hn) ? 1.0f : 0.0f;
        const float vy1 = (iy1 >= 0 && iy1 < Hn) ? 1.0f : 0.0f;
        const float vx0 = (ix0 >= 0 && ix0 < Wn) ? 1.0f : 0.0f;
        const float vx1 = (ix1 >= 0 && ix1 < Wn) ? 1.0f : 0.0f;

        const int iy0c = min(max(iy0, 0), Hn - 1);
        const int iy1c = min(max(iy1, 0), Hn - 1);
        const int ix0c = min(max(ix0, 0), Wn - 1);
        const int ix1c = min(max(ix1, 0), Wn - 1);

        pw0[ki] = m * (1.0f - ly) * (1.0f - lx) * vy0 * vx0;
        pw1[ki] = m * (1.0f - ly) * lx          * vy0 * vx1;
        pw2[ki] = m * ly          * (1.0f - lx) * vy1 * vx0;
        pw3[ki] = m * ly          * lx          * vy1 * vx1;
        const int pa  = iy0c * Wn + ix0c;        // fits 16 bits
        const int dx  = ix1c - ix0c;             // 0/1
        const int dyw = (iy1c - iy0c) * Wn;      // 0/96
        pav[ki] = pa | (dx << 16) | (dyw << 17);
    }

    if (wv == 0) {
#pragma unroll
        for (int ki = 0; ki < Kn; ++ki) pwbuf[(0 * Kn + ki) * NPIX + p] = pw0[ki];
#pragma unroll
        for (int ki = 0; ki < Kn; ++ki) abuf[ki * NPIX + p] = pav[ki];
    } else if (wv == 1) {
#pragma unroll
        for (int ki = 0; ki < Kn; ++ki) pwbuf[(1 * Kn + ki) * NPIX + p] = pw1[ki];
    } else if (wv == 2) {
#pragma unroll
        for (int ki = 0; ki < Kn; ++ki) pwbuf[(2 * Kn + ki) * NPIX + p] = pw2[ki];
    } else {
#pragma unroll
        for (int ki = 0; ki < Kn; ++ki) pwbuf[(3 * Kn + ki) * NPIX + p] = pw3[ki];
    }
}

// ====== K2pp: cross-phase pipelined gather (float2) -> bf16 LDS -> MFMA =======
// R22: issue chunk k+1's gathers BETWEEN the barrier and chunk k's MFMA, so
// load latency hides under the MFMA phase. Value buffers vA/vB (18 floats
// each) keep the pipeline static (rule #20). Base = K2p (VGPR 80) so +36
// stays inside the 128-reg 4-wave bin.
__global__ __launch_bounds__(256, 2) void dcn_k2pp(
    const float2* __restrict__ x2,
    const short* __restrict__ wpk2m,
    const float* __restrict__ bias,
    const float* __restrict__ pwbuf,
    const int*   __restrict__ abuf,
    float* __restrict__ out)
{
    __shared__ short smp[32 * 64 * 8];   // 32 KB

    const int tid  = threadIdx.x;
    const int lane = tid & 63;
    const int wv   = tid >> 6;           // 0..3 = px-tile

    const int bid = (blockIdx.x & 7) * BLK_PER_B + (blockIdx.x >> 3);

    const int p0  = bid * 64;
    const int b   = p0 / HWn;
    const int hwb = p0 % HWn;
    const int p   = p0 + lane;

    const float2* xb2 = x2 + (size_t)b * (Cn * HWn);

    float pw0[Kn], pw1[Kn], pw2[Kn], pw3[Kn];
    int   pav[Kn];
#pragma unroll
    for (int ki = 0; ki < Kn; ++ki) pw0[ki] = pwbuf[(0 * Kn + ki) * NPIX + p];
#pragma unroll
    for (int ki = 0; ki < Kn; ++ki) pw1[ki] = pwbuf[(1 * Kn + ki) * NPIX + p];
#pragma unroll
    for (int ki = 0; ki < Kn; ++ki) pw2[ki] = pwbuf[(2 * Kn + ki) * NPIX + p];
#pragma unroll
    for (int ki = 0; ki < Kn; ++ki) pw3[ki] = pwbuf[(3 * Kn + ki) * NPIX + p];
#pragma unroll
    for (int ki = 0; ki < Kn; ++ki) pav[ki] = abuf[ki * NPIX + p];

    f32x4 acc[4];
#pragma unroll
    for (int oct = 0; oct < 4; ++oct) acc[oct] = (f32x4){0.f, 0.f, 0.f, 0.f};

    const short8v* afrags = (const short8v*)wpk2m;

#define GATHER(V, CH)                                                          \
    {                                                                          \
        _Pragma("unroll")                                                      \
        for (int cc = 0; cc < 2; ++cc) {                                       \
            const int cl = (wv << 1) | cc;                                     \
            const float2* xc2 = xb2 + ((CH) * 8 + cl) * HWn;                   \
            _Pragma("unroll")                                                  \
            for (int ki = 0; ki < Kn; ++ki) {                                  \
                const int av  = pav[ki];                                       \
                const int pa  = av & 0xFFFF;                                   \
                const int dx  = (av >> 16) & 1;                                \
                const int dyw = av >> 17;                                      \
                const float2 q0 = xc2[pa];                                     \
                const float2 q1 = xc2[pa + dyw];                               \
                V[cc][ki] = pw0[ki] * q0.x + pw1[ki] * (dx ? q0.y : q0.x)      \
                          + pw2[ki] * q1.x + pw3[ki] * (dx ? q1.y : q1.x);     \
            }                                                                  \
        }                                                                      \
    }

#define STORE(V)                                                               \
    {                                                                          \
        _Pragma("unroll")                                                      \
        for (int cc = 0; cc < 2; ++cc) {                                       \
            const int cl = (wv << 1) | cc;                                     \
            unsigned short hi[Kn], lo[Kn];                                     \
            _Pragma("unroll")                                                  \
            for (int ki = 0; ki < Kn; ++ki) {                                  \
                hi[ki] = bf16_rne(V[cc][ki]);                                  \
                lo[ki] = bf16_rne(V[cc][ki] - bf16_back(hi[ki]));              \
            }                                                                  \
            short8v h0, h1, l0, l1;                                            \
            _Pragma("unroll")                                                  \
            for (int j = 0; j < 8; ++j) {                                      \
                h0[j] = (short)hi[j]; l0[j] = (short)lo[j];                    \
            }                                                                  \
            h1 = (short8v){(short)hi[8], 0, 0, 0, 0, 0, 0, 0};                 \
            l1 = (short8v){(short)lo[8], 0, 0, 0, 0, 0, 0, 0};                 \
            const int r0 = cl * 4;                                             \
            *(short8v*)&smp[((r0 + 0) * 64 + lane) * 8] = h0;                  \
            *(short8v*)&smp[((r0 + 1) * 64 + lane) * 8] = h1;                  \
            *(short8v*)&smp[((r0 + 2) * 64 + lane) * 8] = l0;                  \
            *(short8v*)&smp[((r0 + 3) * 64 + lane) * 8] = l1;                  \
        }                                                                      \
    }

#define MFMA_CHUNK(CH)                                                         \
    {                                                                          \
        _Pragma("unroll")                                                      \
        for (int ks = 0; ks < 8; ++ks) {                                       \
            const short8v bfrag = *(const short8v*)                            \
                &smp[((ks * 4 + (lane >> 4)) * 64 + wv * 16 + (lane & 15)) * 8]; \
            _Pragma("unroll")                                                  \
            for (int oct = 0; oct < 4; ++oct) {                                \
                const short8v afrag =                                          \
                    afrags[((((CH) * 8 + ks) * 4) + oct) * 64 + lane];         \
                acc[oct] = __builtin_amdgcn_mfma_f32_16x16x32_bf16(            \
                    afrag, bfrag, acc[oct], 0, 0, 0);                          \
            }                                                                  \
        }                                                                      \
    }

    float vA[2][Kn], vB[2][Kn];
    GATHER(vA, 0);
    for (int k = 0; k < 8; k += 2) {
        STORE(vA);
        __syncthreads();
        GATHER(vB, k + 1);          // loads fly during MFMA(k)
        MFMA_CHUNK(k);
        __syncthreads();
        STORE(vB);
        __syncthreads();
        if (k + 2 < 8) GATHER(vA, k + 2);   // loads fly during MFMA(k+1)
        MFMA_CHUNK(k + 1);
        __syncthreads();
    }

#undef GATHER
#undef STORE
#undef MFMA_CHUNK

    const int pxl = wv * 16 + (lane & 15);
    float* ob = out + b * (OCn * HWn) + hwb + pxl;
#pragma unroll
    for (int oct = 0; oct < 4; ++oct) {
#pragma unroll
        for (int r = 0; r < 4; ++r) {
            const int oc = oct * 16 + ((lane >> 4) & 3) * 4 + r;
            ob[oc * HWn] = acc[oct][r] + bias[oc];
        }
    }
}

// ====== K2: R19 4-load variant (fallback when ws too small for x2) ============
__global__ __launch_bounds__(256, 2) void dcn_k2(
    const float* __restrict__ x,
    const short* __restrict__ wpk2m,
    const float* __restrict__ bias,
    const float* __restrict__ pwbuf,
    const int*   __restrict__ abuf,
    float* __restrict__ out)
{
    __shared__ short smp[32 * 64 * 8];   // 32 KB

    const int tid  = threadIdx.x;
    const int lane = tid & 63;
    const int wv   = tid >> 6;

    const int bid = (blockIdx.x & 7) * BLK_PER_B + (blockIdx.x >> 3);

    const int p0  = bid * 64;
    const int b   = p0 / HWn;
    const int hwb = p0 % HWn;
    const int p   = p0 + lane;

    const float* xb = x + b * (Cn * HWn);

    float pw0[Kn], pw1[Kn], pw2[Kn], pw3[Kn];
    int   pav[Kn];
#pragma unroll
    for (int ki = 0; ki < Kn; ++ki) pw0[ki] = pwbuf[(0 * Kn + ki) * NPIX + p];
#pragma unroll
    for (int ki = 0; ki < Kn; ++ki) pw1[ki] = pwbuf[(1 * Kn + ki) * NPIX + p];
#pragma unroll
    for (int ki = 0; ki < Kn; ++ki) pw2[ki] = pwbuf[(2 * Kn + ki) * NPIX + p];
#pragma unroll
    for (int ki = 0; ki < Kn; ++ki) pw3[ki] = pwbuf[(3 * Kn + ki) * NPIX + p];
#pragma unroll
    for (int ki = 0; ki < Kn; ++ki) pav[ki] = abuf[ki * NPIX + p];

    f32x4 acc[4];
#pragma unroll
    for (int oct = 0; oct < 4; ++oct) acc[oct] = (f32x4){0.f, 0.f, 0.f, 0.f};

    const short8v* afrags = (const short8v*)wpk2m;

    for (int chunk = 0; chunk < 8; ++chunk) {
#pragma unroll
        for (int cc = 0; cc < 2; ++cc) {
            const int cl = (wv << 1) | cc;
            const float* xc = xb + (chunk * 8 + cl) * HWn;
            unsigned short hi[Kn], lo[Kn];
#pragma unroll
            for (int ki = 0; ki < Kn; ++ki) {
                const int av  = pav[ki];
                const int pa  = av & 0xFFFF;
                const int dx  = (av >> 16) & 1;
                const int dyw = av >> 17;
                const float* bp = xc + pa;
                const float v = pw0[ki] * bp[0] + pw1[ki] * bp[dx]
                              + pw2[ki] * bp[dyw] + pw3[ki] * bp[dyw + dx];
                hi[ki] = bf16_rne(v);
                lo[ki] = bf16_rne(v - bf16_back(hi[ki]));
            }
            short8v h0, h1, l0, l1;
#pragma unroll
            for (int j = 0; j < 8; ++j) { h0[j] = (short)hi[j]; l0[j] = (short)lo[j]; }
            h1 = (short8v){(short)hi[8], 0, 0, 0, 0, 0, 0, 0};
            l1 = (short8v){(short)lo[8], 0, 0, 0, 0, 0, 0, 0};
            const int r0 = cl * 4;
            *(short8v*)&smp[((r0 + 0) * 64 + lane) * 8] = h0;
            *(short8v*)&smp[((r0 + 1) * 64 + lane) * 8] = h1;
            *(short8v*)&smp[((r0 + 2) * 64 + lane) * 8] = l0;
            *(short8v*)&smp[((r0 + 3) * 64 + lane) * 8] = l1;
        }
        __syncthreads();

#pragma unroll
        for (int ks = 0; ks < 8; ++ks) {
            const short8v bfrag = *(const short8v*)
                &smp[((ks * 4 + (lane >> 4)) * 64 + wv * 16 + (lane & 15)) * 8];
#pragma unroll
            for (int oct = 0; oct < 4; ++oct) {
                const short8v afrag =
                    afrags[(((chunk * 8 + ks) * 4) + oct) * 64 + lane];
                acc[oct] = __builtin_amdgcn_mfma_f32_16x16x32_bf16(
                    afrag, bfrag, acc[oct], 0, 0, 0);
            }
        }
        __syncthreads();
    }

    const int pxl = wv * 16 + (lane & 15);
    float* ob = out + b * (OCn * HWn) + hwb + pxl;
#pragma unroll
    for (int oct = 0; oct < 4; ++oct) {
#pragma unroll
        for (int r = 0; r < 4; ++r) {
            const int oc = oct * 16 + ((lane >> 4) & 3) * 4 + r;
            ob[oc * HWn] = acc[oct][r] + bias[oc];
        }
    }
}

// ============================ fallback (R1 single-kernel, if ws too small) ====
__global__ __launch_bounds__(64) void dcn_r1(
    const float* __restrict__ x,
    const float* __restrict__ w_off,
    const float* __restrict__ b_off,
    const float* __restrict__ weight,
    const float* __restrict__ bias,
    float* __restrict__ out)
{
    const int p  = blockIdx.x * 64 + threadIdx.x;
    const int b  = p / HWn;
    const int hw = p % HWn;
    const int ho = hw / Wn;
    const int wo = hw % Wn;
    const float* xb = x + b * (Cn * HWn);

    float om[OFFCn];
#pragma unroll
    for (int j = 0; j < OFFCn; ++j) om[j] = b_off[j];

    int   toff[Kn];
    float tval[Kn];
#pragma unroll
    for (int ki = 0; ki < Kn; ++ki) {
        const int yy = ho + ki / 3 - 1, xx = wo + ki % 3 - 1;
        const bool v = (yy >= 0) && (yy < Hn) && (xx >= 0) && (xx < Wn);
        toff[ki] = min(max(yy, 0), Hn - 1) * Wn + min(max(xx, 0), Wn - 1);
        tval[ki] = v ? 1.0f : 0.0f;
    }
    for (int c = 0; c < Cn; ++c) {
        const float* xc = xb + c * HWn;
        float xk[Kn];
#pragma unroll
        for (int ki = 0; ki < Kn; ++ki) xk[ki] = xc[toff[ki]] * tval[ki];
        const float* wc = w_off + c * Kn;
#pragma unroll
        for (int och = 0; och < OFFCn; ++och) {
            const float* wp = wc + och * (Cn * Kn);
            float a = om[och];
#pragma unroll
            for (int ki = 0; ki < Kn; ++ki) a = fmaf(xk[ki], wp[ki], a);
            om[och] = a;
        }
    }
    float pw0[Kn], pw1[Kn], pw2[Kn], pw3[Kn];
    int   pa[Kn], pdx[Kn], pdyw[Kn];
#pragma unroll
    for (int ki = 0; ki < Kn; ++ki) {
        const float py = om[ki]      + (float)(ki / 3 + ho - 1);
        const float px = om[Kn + ki] + (float)(ki % 3 + wo - 1);
        const float m  = 1.0f / (1.0f + __expf(-om[2 * Kn + ki]));
        const float y0f = floorf(py), x0f = floorf(px);
        const float ly = py - y0f, lx = px - x0f;
        const int iy0 = (int)y0f, ix0 = (int)x0f;
        const int iy1 = iy0 + 1,  ix1 = ix0 + 1;
        const float vy0 = (iy0 >= 0 && iy0 < Hn) ? 1.0f : 0.0f;
        const float vy1 = (iy1 >= 0 && iy1 < Hn) ? 1.0f : 0.0f;
        const float vx0 = (ix0 >= 0 && ix0 < Wn) ? 1.0f : 0.0f;
        const float vx1 = (ix1 >= 0 && ix1 < Wn) ? 1.0f : 0.0f;
        const int iy0c = min(max(iy0, 0), Hn - 1);
        const int iy1c = min(max(iy1, 0), Hn - 1);
        const int ix0c = min(max(ix0, 0), Wn - 1);
        const int ix1c = min(max(ix1, 0), Wn - 1);
        pw0[ki] = m * (1.0f - ly) * (1.0f - lx) * vy0 * vx0;
        pw1[ki] = m * (1.0f - ly) * lx          * vy0 * vx1;
        pw2[ki] = m * ly          * (1.0f - lx) * vy1 * vx0;
        pw3[ki] = m * ly          * lx          * vy1 * vx1;
        pa[ki]   = iy0c * Wn + ix0c;
        pdx[ki]  = ix1c - ix0c;
        pdyw[ki] = (iy1c - iy0c) * Wn;
    }
    float acc[OCn];
#pragma unroll
    for (int oc = 0; oc < OCn; ++oc) acc[oc] = bias[oc];
    for (int c = 0; c < Cn; ++c) {
        const float* xc = xb + c * HWn;
        float s[Kn];
#pragma unroll
        for (int ki = 0; ki < Kn; ++ki) {
            const float* bp = xc + pa[ki];
            s[ki] = pw0[ki] * bp[0] + pw1[ki] * bp[pdx[ki]]
                  + pw2[ki] * bp[pdyw[ki]] + pw3[ki] * bp[pdyw[ki] + pdx[ki]];
        }
        const float* wc = weight + c * Kn;
#pragma unroll
        for (int oc = 0; oc < OCn; ++oc) {
            const float* wp = wc + oc * (Cn * Kn);
            float a = acc[oc];
#pragma unroll
            for (int ki = 0; ki < Kn; ++ki) a = fmaf(s[ki], wp[ki], a);
            acc[oc] = a;
        }
    }
    float* ob = out + b * (OCn * HWn) + hw;
#pragma unroll
    for (int oc = 0; oc < OCn; ++oc) ob[oc * HWn] = acc[oc];
}

extern "C" void kernel_launch(void* const* d_in, const int* in_sizes, int n_in,
                              void* d_out, int out_size, void* d_ws, size_t ws_size,
                              hipStream_t stream) {
    const float* x      = (const float*)d_in[0];
    const float* w_off  = (const float*)d_in[1];
    const float* b_off  = (const float*)d_in[2];
    const float* weight = (const float*)d_in[3];
    const float* bias   = (const float*)d_in[4];
    float* out = (float*)d_out;

    if (ws_size >= WS_BYTES) {
        float* pwbuf = (float*)d_ws;
        int*   abuf  = (int*)((float*)d_ws + 36 * NPIX);
        float* wpk1  = (float*)d_ws + 45 * NPIX;
        short* wpk2m = (short*)(wpk1 + WPK1_N);
        hipLaunchKernelGGL(dcn_wprep, dim3(64), dim3(256), 0, stream,
                           w_off, weight, wpk1, wpk2m);
        hipLaunchKernelGGL(dcn_k1, dim3(PGRPS), dim3(256), 0, stream,
                           x, wpk1, b_off, pwbuf, abuf);
        if (ws_size >= WS2_BYTES) {
            float2* x2 = (float2*)((char*)d_ws + WS_BYTES);
            hipLaunchKernelGGL(dcn_xprep, dim3((X2_ELEMS + 255) / 256), dim3(256),
                               0, stream, x, x2);
            hipLaunchKernelGGL(dcn_k2pp, dim3(PGRPS), dim3(256), 0, stream,
                               x2, wpk2m, bias, pwbuf, abuf, out);
        } else {
            hipLaunchKernelGGL(dcn_k2, dim3(PGRPS), dim3(256), 0, stream,
                               x, wpk2m, bias, pwbuf, abuf, out);
        }
    } else {
        hipLaunchKernelGGL(dcn_r1, dim3(NPIX / 64), dim3(64), 0, stream,
                           x, w_off, b_off, weight, bias, out);
    }
}

// Round 23
// 230.746 us; speedup vs baseline: 1.0433x; 1.0433x over previous
//
#include <hip/hip_runtime.h>
#include <math.h>

#define Bn 8
#define Cn 64
#define Hn 96
#define Wn 96
#define HWn (Hn*Wn)
#define OCn 64
#define Kn 9
#define OFFCn 27
#define NPIX (Bn*HWn)        // 73728 = 1152*64
#define PGRPS (NPIX/64)      // 1152 pixel groups (64 px each)
#define BLK_PER_B (HWn/64)   // 144 blocks per batch image

// ws layout (dwords): pwbuf[36*NPIX] | abuf[9*NPIX] | wpk1[15552] | wpk2m shorts
#define WPK1_N 15552
#define WPK2M_SHORTS 131072
#define WS_DWORDS (45*NPIX + WPK1_N + WPK2M_SHORTS/2)
#define WS_BYTES  ((size_t)WS_DWORDS*4)   // ~13.9 MB

typedef __attribute__((ext_vector_type(8))) short short8v;
typedef __attribute__((ext_vector_type(4))) short short4v;
typedef __attribute__((ext_vector_type(4))) float f32x4;

static __device__ __forceinline__ unsigned short bf16_rne(float f) {
    unsigned int u = __float_as_uint(f);
    return (unsigned short)((u + 0x7FFFu + ((u >> 16) & 1u)) >> 16);
}
static __device__ __forceinline__ float bf16_back(unsigned short h) {
    return __uint_as_float(((unsigned int)h) << 16);
}

// ============ wprep: wpk1 stream (offset conv) + wpk2m MFMA A-frags ===========
__global__ __launch_bounds__(256) void dcn_wprep(
    const float* __restrict__ w_off,
    const float* __restrict__ weight,
    float* __restrict__ wpk1,
    short* __restrict__ wpk2m)
{
    const int g = blockIdx.x * 256 + threadIdx.x;   // 64 blocks -> 16384
    if (g < WPK1_N) {
        const int c_all = g / 243;
        const int och   = (g % 243) / 9;
        const int ki    = g % 9;
        wpk1[g] = w_off[(och * 64 + c_all) * 9 + ki];
    }
    if (g < WPK2M_SHORTS / 8) {
        const int lane = g & 63;
        const int oct  = (g >> 6) & 3;
        const int c    = g >> 8;
        const int oc   = oct * 16 + (lane & 15);
        const float* wsrc = weight + (oc * 64 + c) * 9;
        short8v v;
#pragma unroll
        for (int j = 0; j < 8; ++j) {
            const int s = ((lane >> 4) & 3) * 8 + j;
            float f = 0.0f;
            if (s <= 8)                  f = wsrc[s];
            else if (s >= 16 && s <= 24) f = wsrc[s - 16];
            v[j] = (short)bf16_rne(f);
        }
        ((short8v*)wpk2m)[g] = v;
    }
}

// ============================ K1: offset conv + sampling params (swizzled) ====
__global__ __launch_bounds__(256, 2) void dcn_k1(
    const float* __restrict__ x,
    const float* __restrict__ wpk1,
    const float* __restrict__ b_off,
    float* __restrict__ pwbuf,
    int*   __restrict__ abuf)
{
    __shared__ float lds[4 * 64 * OFFCn];   // 27.6 KB

    const int tid  = threadIdx.x;
    const int lane = tid & 63;
    const int wv   = tid >> 6;
    const int cbase = __builtin_amdgcn_readfirstlane(wv * 16);

    const int bid = (blockIdx.x & 7) * BLK_PER_B + (blockIdx.x >> 3);

    const int p  = bid * 64 + lane;
    const int b  = p / HWn;
    const int hw = p % HWn;
    const int ho = hw / Wn;
    const int wo = hw % Wn;

    const float* xb = x + b * (Cn * HWn);

    int   toff[Kn];
    float tval[Kn];
#pragma unroll
    for (int ki = 0; ki < Kn; ++ki) {
        const int yy = ho + ki / 3 - 1, xx = wo + ki % 3 - 1;
        const bool v = (yy >= 0) && (yy < Hn) && (xx >= 0) && (xx < Wn);
        toff[ki] = min(max(yy, 0), Hn - 1) * Wn + min(max(xx, 0), Wn - 1);
        tval[ki] = v ? 1.0f : 0.0f;
    }

    float om[OFFCn];
#pragma unroll
    for (int j = 0; j < OFFCn; ++j) om[j] = 0.0f;

    const float* wstream = wpk1 + cbase * 243;
    for (int ci = 0; ci < 16; ++ci) {
        const float* xc = xb + (cbase + ci) * HWn;
        float xk[Kn];
#pragma unroll
        for (int ki = 0; ki < Kn; ++ki)
            xk[ki] = xc[toff[ki]] * tval[ki];

        const float* wc = wstream + ci * 243;
#pragma unroll
        for (int och = 0; och < OFFCn; ++och) {
            const float* wp = wc + och * 9;
            float a = om[och];
#pragma unroll
            for (int ki = 0; ki < Kn; ++ki)
                a = fmaf(xk[ki], wp[ki], a);
            om[och] = a;
        }
    }

#pragma unroll
    for (int j = 0; j < OFFCn; ++j)
        lds[(wv * 64 + lane) * OFFCn + j] = om[j];
    __syncthreads();
#pragma unroll
    for (int j = 0; j < OFFCn; ++j) {
        float a = b_off[j];
#pragma unroll
        for (int ww = 0; ww < 4; ++ww)
            a += lds[(ww * 64 + lane) * OFFCn + j];
        om[j] = a;
    }

    float pw0[Kn], pw1[Kn], pw2[Kn], pw3[Kn];
    int   pav[Kn];
#pragma unroll
    for (int ki = 0; ki < Kn; ++ki) {
        const float py = om[ki]      + (float)(ki / 3 + ho - 1);
        const float px = om[Kn + ki] + (float)(ki % 3 + wo - 1);
        const float m  = 1.0f / (1.0f + __expf(-om[2 * Kn + ki]));

        const float y0f = floorf(py), x0f = floorf(px);
        const float ly = py - y0f, lx = px - x0f;
        const int iy0 = (int)y0f, ix0 = (int)x0f;
        const int iy1 = iy0 + 1,  ix1 = ix0 + 1;

        const float vy0 = (iy0 >= 0 && iy0 < Hn) ? 1.0f : 0.0f;
        const float vy1 = (iy1 >= 0 && iy1 < Hn) ? 1.0f : 0.0f;
        const float vx0 = (ix0 >= 0 && ix0 < Wn) ? 1.0f : 0.0f;
        const float vx1 = (ix1 >= 0 && ix1 < Wn) ? 1.0f : 0.0f;

        const int iy0c = min(max(iy0, 0), Hn - 1);
        const int iy1c = min(max(iy1, 0), Hn - 1);
        const int ix0c = min(max(ix0, 0), Wn - 1);
        const int ix1c = min(max(ix1, 0), Wn - 1);

        pw0[ki] = m * (1.0f - ly) * (1.0f - lx) * vy0 * vx0;
        pw1[ki] = m * (1.0f - ly) * lx          * vy0 * vx1;
        pw2[ki] = m * ly          * (1.0f - lx) * vy1 * vx0;
        pw3[ki] = m * ly          * lx          * vy1 * vx1;
        const int pa  = iy0c * Wn + ix0c;        // fits 16 bits
        const int dx  = ix1c - ix0c;             // 0/1
        const int dyw = (iy1c - iy0c) * Wn;      // 0/96
        pav[ki] = pa | (dx << 16) | (dyw << 17);
    }

    if (wv == 0) {
#pragma unroll
        for (int ki = 0; ki < Kn; ++ki) pwbuf[(0 * Kn + ki) * NPIX + p] = pw0[ki];
#pragma unroll
        for (int ki = 0; ki < Kn; ++ki) abuf[ki * NPIX + p] = pav[ki];
    } else if (wv == 1) {
#pragma unroll
        for (int ki = 0; ki < Kn; ++ki) pwbuf[(1 * Kn + ki) * NPIX + p] = pw1[ki];
    } else if (wv == 2) {
#pragma unroll
        for (int ki = 0; ki < Kn; ++ki) pwbuf[(2 * Kn + ki) * NPIX + p] = pw2[ki];
    } else {
#pragma unroll
        for (int ki = 0; ki < Kn; ++ki) pwbuf[(3 * Kn + ki) * NPIX + p] = pw3[ki];
    }
}

// ====== K2w: BARRIER-FREE wave-private gather -> bf16 LDS -> MFMA =============
// (R21 config -- best measured: total 231 us.) Each wave owns 32 px; lanes
// 0-31 sample ki 0-4, lanes 32-63 ki 4-8 (ki4 duplicated, same value/address).
// Wave-private LDS double buffers -> no s_barrier at all.
__global__ __launch_bounds__(128, 2) void dcn_k2w(
    const float* __restrict__ x,
    const short* __restrict__ wpk2m,
    const float* __restrict__ bias,
    const float* __restrict__ pwbuf,
    const int*   __restrict__ abuf,
    float* __restrict__ out)
{
    __shared__ short smp[2 * 2 * 2048];   // [wave][buf][8 rows x 32 px x 8] = 16 KB

    const int tid  = threadIdx.x;
    const int lane = tid & 63;
    const int wv   = tid >> 6;            // 0..1
    const int q    = lane >> 5;           // ki-half
    const int px   = lane & 31;
    const int kb   = q * 4;

    const int bid = (blockIdx.x & 7) * BLK_PER_B + (blockIdx.x >> 3);
    const int p0  = bid * 64 + wv * 32;
    const int b   = p0 / HWn;
    const int hwb = p0 % HWn;
    const int p   = p0 + px;

    const float* xb = x + b * (Cn * HWn);
    short* myA = smp + wv * 4096;
    short* myB = myA + 2048;

    {
        short8v z = (short8v){0, 0, 0, 0, 0, 0, 0, 0};
#pragma unroll
        for (int t = 0; t < 2; ++t) {
            const int idx = t * 64 + lane;
            const int r   = 1 + 2 * (idx >> 5);
            const int pp  = idx & 31;
            *(short8v*)&myA[(r * 32 + pp) * 8] = z;
            *(short8v*)&myB[(r * 32 + pp) * 8] = z;
        }
    }

    float pw0[5], pw1[5], pw2[5], pw3[5];
    int   pav[5];
#pragma unroll
    for (int i = 0; i < 5; ++i) pw0[i] = pwbuf[(0 * Kn + kb + i) * NPIX + p];
#pragma unroll
    for (int i = 0; i < 5; ++i) pw1[i] = pwbuf[(1 * Kn + kb + i) * NPIX + p];
#pragma unroll
    for (int i = 0; i < 5; ++i) pw2[i] = pwbuf[(2 * Kn + kb + i) * NPIX + p];
#pragma unroll
    for (int i = 0; i < 5; ++i) pw3[i] = pwbuf[(3 * Kn + kb + i) * NPIX + p];
#pragma unroll
    for (int i = 0; i < 5; ++i) pav[i] = abuf[(kb + i) * NPIX + p];

    f32x4 acc[2][4];
#pragma unroll
    for (int t = 0; t < 2; ++t)
#pragma unroll
        for (int oct = 0; oct < 4; ++oct)
            acc[t][oct] = (f32x4){0.f, 0.f, 0.f, 0.f};

    const short8v* afrags = (const short8v*)wpk2m;
    const int r4  = lane >> 4;
    const int c16 = lane & 15;

    for (int it = 0; it < 16; ++it) {
        const int ch0 = it * 4;

#pragma unroll
        for (int c = 0; c < 2; ++c) {
            const float* xc = xb + (ch0 + c) * HWn;
            unsigned short h[5], l[5];
#pragma unroll
            for (int i = 0; i < 5; ++i) {
                const int av  = pav[i];
                const int pa  = av & 0xFFFF;
                const int dx  = (av >> 16) & 1;
                const int dyw = av >> 17;
                const float* bp = xc + pa;
                const float v = pw0[i] * bp[0] + pw1[i] * bp[dx]
                              + pw2[i] * bp[dyw] + pw3[i] * bp[dyw + dx];
                h[i] = bf16_rne(v);
                l[i] = bf16_rne(v - bf16_back(h[i]));
            }
            short4v h4 = (short4v){(short)h[0], (short)h[1], (short)h[2], (short)h[3]};
            short4v l4 = (short4v){(short)l[0], (short)l[1], (short)l[2], (short)l[3]};
            *(short4v*)&myA[((c * 4 + 0) * 32 + px) * 8 + q * 4] = h4;
            *(short4v*)&myA[((c * 4 + 2) * 32 + px) * 8 + q * 4] = l4;
            myA[((c * 4 + 0 + q) * 32 + px) * 8 + (q ? 0 : 4)] = (short)h[4];
            myA[((c * 4 + 2 + q) * 32 + px) * 8 + (q ? 0 : 4)] = (short)l[4];
        }

#pragma unroll
        for (int c = 0; c < 2; ++c) {
            const float* xc = xb + (ch0 + 2 + c) * HWn;
            unsigned short h[5], l[5];
#pragma unroll
            for (int i = 0; i < 5; ++i) {
                const int av  = pav[i];
                const int pa  = av & 0xFFFF;
                const int dx  = (av >> 16) & 1;
                const int dyw = av >> 17;
                const float* bp = xc + pa;
                const float v = pw0[i] * bp[0] + pw1[i] * bp[dx]
                              + pw2[i] * bp[dyw] + pw3[i] * bp[dyw + dx];
                h[i] = bf16_rne(v);
                l[i] = bf16_rne(v - bf16_back(h[i]));
            }
            short4v h4 = (short4v){(short)h[0], (short)h[1], (short)h[2], (short)h[3]};
            short4v l4 = (short4v){(short)l[0], (short)l[1], (short)l[2], (short)l[3]};
            *(short4v*)&myB[((c * 4 + 0) * 32 + px) * 8 + q * 4] = h4;
            *(short4v*)&myB[((c * 4 + 2) * 32 + px) * 8 + q * 4] = l4;
            myB[((c * 4 + 0 + q) * 32 + px) * 8 + (q ? 0 : 4)] = (short)h[4];
            myB[((c * 4 + 2 + q) * 32 + px) * 8 + (q ? 0 : 4)] = (short)l[4];
        }

#pragma unroll
        for (int c = 0; c < 2; ++c) {
            const short8v bf0 = *(const short8v*)&myA[((c * 4 + r4) * 32 + c16) * 8];
            const short8v bf1 = *(const short8v*)&myA[((c * 4 + r4) * 32 + 16 + c16) * 8];
#pragma unroll
            for (int oct = 0; oct < 4; ++oct) {
                const short8v af = afrags[(((ch0 + c) * 4) + oct) * 64 + lane];
                acc[0][oct] = __builtin_amdgcn_mfma_f32_16x16x32_bf16(af, bf0, acc[0][oct], 0, 0, 0);
                acc[1][oct] = __builtin_amdgcn_mfma_f32_16x16x32_bf16(af, bf1, acc[1][oct], 0, 0, 0);
            }
        }

#pragma unroll
        for (int c = 0; c < 2; ++c) {
            const short8v bf0 = *(const short8v*)&myB[((c * 4 + r4) * 32 + c16) * 8];
            const short8v bf1 = *(const short8v*)&myB[((c * 4 + r4) * 32 + 16 + c16) * 8];
#pragma unroll
            for (int oct = 0; oct < 4; ++oct) {
                const short8v af = afrags[(((ch0 + 2 + c) * 4) + oct) * 64 + lane];
                acc[0][oct] = __builtin_amdgcn_mfma_f32_16x16x32_bf16(af, bf0, acc[0][oct], 0, 0, 0);
                acc[1][oct] = __builtin_amdgcn_mfma_f32_16x16x32_bf16(af, bf1, acc[1][oct], 0, 0, 0);
            }
        }
    }

#pragma unroll
    for (int t = 0; t < 2; ++t) {
        float* ob = out + b * (OCn * HWn) + hwb + t * 16 + c16;
#pragma unroll
        for (int oct = 0; oct < 4; ++oct) {
#pragma unroll
            for (int r = 0; r < 4; ++r) {
                const int oc = oct * 16 + r4 * 4 + r;
                ob[oc * HWn] = acc[t][oct][r] + bias[oc];
            }
        }
    }
}

// ============================ fallback (R1 single-kernel, if ws too small) ====
__global__ __launch_bounds__(64) void dcn_r1(
    const float* __restrict__ x,
    const float* __restrict__ w_off,
    const float* __restrict__ b_off,
    const float* __restrict__ weight,
    const float* __restrict__ bias,
    float* __restrict__ out)
{
    const int p  = blockIdx.x * 64 + threadIdx.x;
    const int b  = p / HWn;
    const int hw = p % HWn;
    const int ho = hw / Wn;
    const int wo = hw % Wn;
    const float* xb = x + b * (Cn * HWn);

    float om[OFFCn];
#pragma unroll
    for (int j = 0; j < OFFCn; ++j) om[j] = b_off[j];

    int   toff[Kn];
    float tval[Kn];
#pragma unroll
    for (int ki = 0; ki < Kn; ++ki) {
        const int yy = ho + ki / 3 - 1, xx = wo + ki % 3 - 1;
        const bool v = (yy >= 0) && (yy < Hn) && (xx >= 0) && (xx < Wn);
        toff[ki] = min(max(yy, 0), Hn - 1) * Wn + min(max(xx, 0), Wn - 1);
        tval[ki] = v ? 1.0f : 0.0f;
    }
    for (int c = 0; c < Cn; ++c) {
        const float* xc = xb + c * HWn;
        float xk[Kn];
#pragma unroll
        for (int ki = 0; ki < Kn; ++ki) xk[ki] = xc[toff[ki]] * tval[ki];
        const float* wc = w_off + c * Kn;
#pragma unroll
        for (int och = 0; och < OFFCn; ++och) {
            const float* wp = wc + och * (Cn * Kn);
            float a = om[och];
#pragma unroll
            for (int ki = 0; ki < Kn; ++ki) a = fmaf(xk[ki], wp[ki], a);
            om[och] = a;
        }
    }
    float pw0[Kn], pw1[Kn], pw2[Kn], pw3[Kn];
    int   pa[Kn], pdx[Kn], pdyw[Kn];
#pragma unroll
    for (int ki = 0; ki < Kn; ++ki) {
        const float py = om[ki]      + (float)(ki / 3 + ho - 1);
        const float px = om[Kn + ki] + (float)(ki % 3 + wo - 1);
        const float m  = 1.0f / (1.0f + __expf(-om[2 * Kn + ki]));
        const float y0f = floorf(py), x0f = floorf(px);
        const float ly = py - y0f, lx = px - x0f;
        const int iy0 = (int)y0f, ix0 = (int)x0f;
        const int iy1 = iy0 + 1,  ix1 = ix0 + 1;
        const float vy0 = (iy0 >= 0 && iy0 < Hn) ? 1.0f : 0.0f;
        const float vy1 = (iy1 >= 0 && iy1 < Hn) ? 1.0f : 0.0f;
        const float vx0 = (ix0 >= 0 && ix0 < Wn) ? 1.0f : 0.0f;
        const float vx1 = (ix1 >= 0 && ix1 < Wn) ? 1.0f : 0.0f;
        const int iy0c = min(max(iy0, 0), Hn - 1);
        const int iy1c = min(max(iy1, 0), Hn - 1);
        const int ix0c = min(max(ix0, 0), Wn - 1);
        const int ix1c = min(max(ix1, 0), Wn - 1);
        pw0[ki] = m * (1.0f - ly) * (1.0f - lx) * vy0 * vx0;
        pw1[ki] = m * (1.0f - ly) * lx          * vy0 * vx1;
        pw2[ki] = m * ly          * (1.0f - lx) * vy1 * vx0;
        pw3[ki] = m * ly          * lx          * vy1 * vx1;
        pa[ki]   = iy0c * Wn + ix0c;
        pdx[ki]  = ix1c - ix0c;
        pdyw[ki] = (iy1c - iy0c) * Wn;
    }
    float acc[OCn];
#pragma unroll
    for (int oc = 0; oc < OCn; ++oc) acc[oc] = bias[oc];
    for (int c = 0; c < Cn; ++c) {
        const float* xc = xb + c * HWn;
        float s[Kn];
#pragma unroll
        for (int ki = 0; ki < Kn; ++ki) {
            const float* bp = xc + pa[ki];
            s[ki] = pw0[ki] * bp[0] + pw1[ki] * bp[pdx[ki]]
                  + pw2[ki] * bp[pdyw[ki]] + pw3[ki] * bp[pdyw[ki] + pdx[ki]];
        }
        const float* wc = weight + c * Kn;
#pragma unroll
        for (int oc = 0; oc < OCn; ++oc) {
            const float* wp = wc + oc * (Cn * Kn);
            float a = acc[oc];
#pragma unroll
            for (int ki = 0; ki < Kn; ++ki) a = fmaf(s[ki], wp[ki], a);
            acc[oc] = a;
        }
    }
    float* ob = out + b * (OCn * HWn) + hw;
#pragma unroll
    for (int oc = 0; oc < OCn; ++oc) ob[oc * HWn] = acc[oc];
}

extern "C" void kernel_launch(void* const* d_in, const int* in_sizes, int n_in,
                              void* d_out, int out_size, void* d_ws, size_t ws_size,
                              hipStream_t stream) {
    const float* x      = (const float*)d_in[0];
    const float* w_off  = (const float*)d_in[1];
    const float* b_off  = (const float*)d_in[2];
    const float* weight = (const float*)d_in[3];
    const float* bias   = (const float*)d_in[4];
    float* out = (float*)d_out;

    if (ws_size >= WS_BYTES) {
        float* pwbuf = (float*)d_ws;
        int*   abuf  = (int*)((float*)d_ws + 36 * NPIX);
        float* wpk1  = (float*)d_ws + 45 * NPIX;
        short* wpk2m = (short*)(wpk1 + WPK1_N);
        hipLaunchKernelGGL(dcn_wprep, dim3(64), dim3(256), 0, stream,
                           w_off, weight, wpk1, wpk2m);
        hipLaunchKernelGGL(dcn_k1, dim3(PGRPS), dim3(256), 0, stream,
                           x, wpk1, b_off, pwbuf, abuf);
        hipLaunchKernelGGL(dcn_k2w, dim3(PGRPS), dim3(128), 0, stream,
                           x, wpk2m, bias, pwbuf, abuf, out);
    } else {
        hipLaunchKernelGGL(dcn_r1, dim3(NPIX / 64), dim3(64), 0, stream,
                           x, w_off, b_off, weight, bias, out);
    }
}